// Round 1
// 549.702 us; speedup vs baseline: 1.0401x; 1.0401x over previous
//
#include <hip/hip_runtime.h>
#include <hip/hip_bf16.h>
#include <math.h>

// Problem constants
#define B_   512
#define NS_  2
#define S_   128
#define H_   768
#define DS_  384
#define NL_  40
#define H3_  (3*H_)      // 2304
#define TEMP_ 0.05f
#define ALPHA_ 0.15f
#define GAMMA_ 7.5f
#define EPS_ 1e-8f

typedef __attribute__((ext_vector_type(8))) short bf8_t;
typedef __attribute__((ext_vector_type(4))) short s4_t;
typedef __attribute__((ext_vector_type(4))) float f4_t;

#define LDSPAD 40   // bf16 row stride for 32-wide k tiles (80B, 16B-aligned)

// ---------------- helpers ----------------

__device__ __forceinline__ short bfbits(float x) {
    __hip_bfloat16 h = __float2bfloat16(x);
    return *reinterpret_cast<short*>(&h);
}

// blockDim == 256 (4 waves). Wave shuffle reduce + 2 barriers (was 8).
__device__ __forceinline__ float block_reduce_sum(float v, float* sh) {
#pragma unroll
    for (int off = 32; off >= 1; off >>= 1) v += __shfl_down(v, off, 64);
    int w = threadIdx.x >> 6;
    if ((threadIdx.x & 63) == 0) sh[w] = v;
    __syncthreads();
    float r = (sh[0] + sh[1]) + (sh[2] + sh[3]);
    __syncthreads();
    return r;
}

__device__ __forceinline__ float block_reduce_max(float v, float* sh) {
#pragma unroll
    for (int off = 32; off >= 1; off >>= 1) v = fmaxf(v, __shfl_down(v, off, 64));
    int w = threadIdx.x >> 6;
    if ((threadIdx.x & 63) == 0) sh[w] = v;
    __syncthreads();
    float r = fmaxf(fmaxf(sh[0], sh[1]), fmaxf(sh[2], sh[3]));
    __syncthreads();
    return r;
}

// ---------------- kernel 1: prep ----------------
// blocks [0,512): gather batch b (block 0 also zeroes acc + done)
// blocks [512,1088):  transpose dense_w (768x768)  -> dwt (768x768)
// blocks [1088,1952): transpose fc_w   (2304x384)  -> fwt (384x2304)
// blocks [1952,2096): transpose cls_w  (2304x40)   -> cwt (48x2304, rows 40..47 zeroed)
// blocks [2096,2608): desc row L2-norm -> desc_nb
__device__ __forceinline__ void transpose_tile(
    const float* __restrict__ in, __hip_bfloat16* __restrict__ out,
    int K, int N, int kt, int nt, int tid, float* tileLds /* 32*33 */)
{
    int k0 = kt * 32, n0 = nt * 32;
    int tx = tid & 31, ty = tid >> 5;   // ty 0..7
#pragma unroll
    for (int i = 0; i < 4; ++i) {
        int k = k0 + ty + i * 8, n = n0 + tx;
        if (k < K && n < N) tileLds[(ty + i*8) * 33 + tx] = in[(size_t)k * N + n];
    }
    __syncthreads();
#pragma unroll
    for (int i = 0; i < 4; ++i) {
        int n = n0 + ty + i * 8, k = k0 + tx;
        if (n < N && k < K) out[(size_t)n * K + k] = __float2bfloat16(tileLds[tx * 33 + ty + i*8]);
    }
}

__global__ __launch_bounds__(256) void prep_kernel(
    const float* __restrict__ bert, const int* __restrict__ eidx,
    const float* __restrict__ dense_w, const float* __restrict__ fc_w,
    const float* __restrict__ cls_w, const float* __restrict__ desc,
    __hip_bfloat16* __restrict__ rh_bf, __hip_bfloat16* __restrict__ toks_bf,
    __hip_bfloat16* __restrict__ dwt, __hip_bfloat16* __restrict__ fwt,
    __hip_bfloat16* __restrict__ cwt, __hip_bfloat16* __restrict__ desc_nb,
    float* __restrict__ acc, int* __restrict__ done)
{
    __shared__ float tileLds[32 * 33];
    int blk = blockIdx.x;
    int t = threadIdx.x;
    if (blk < 512) {
        int b = blk;
        if (b == 0) {
            if (t < 4) acc[t] = 0.0f;
            if (t == 4) *done = 0;
        }
        int e00 = eidx[b*4 + 0];
        int e01 = eidx[b*4 + 1];
        int e10 = eidx[b*4 + 2];
        int e11 = eidx[b*4 + 3];
        const float* s0 = bert + (size_t)b * NS_ * S_ * H_;
        const float* s1 = s0 + (size_t)S_ * H_;
        const float* cls  = s0;
        const float* head = s0 + (size_t)e00 * H_;
        const float* tail = s0 + (size_t)e01 * H_;
        const float* h2a  = s1 + (size_t)e10 * H_;
        const float* h2b  = s1 + (size_t)e11 * H_;
        __hip_bfloat16* rhb = rh_bf + (size_t)b * H3_;
        __hip_bfloat16* tk  = toks_bf + (size_t)b * 4 * H_;
        for (int h = t; h < H_; h += 256) {
            float c  = cls[h];
            float hd = head[h];
            float tl = tail[h];
            rhb[h]        = __float2bfloat16(tanhf(c));
            rhb[H_ + h]   = __float2bfloat16(tanhf(hd));
            rhb[2*H_ + h] = __float2bfloat16(tanhf(tl));
            tk[h]         = __float2bfloat16(hd);
            tk[H_ + h]    = __float2bfloat16(tl);
            tk[2*H_ + h]  = __float2bfloat16(h2a[h]);
            tk[3*H_ + h]  = __float2bfloat16(h2b[h]);
        }
    } else if (blk < 1088) {
        int q = blk - 512;          // 24x24 tiles
        transpose_tile(dense_w, dwt, H_, H_, q / 24, q % 24, t, tileLds);
    } else if (blk < 1952) {
        int q = blk - 1088;         // 72x12 tiles
        transpose_tile(fc_w, fwt, H3_, DS_, q / 12, q % 12, t, tileLds);
    } else if (blk < 2096) {
        int q = blk - 1952;         // 72x2 tiles
        int kt = q / 2, nt = q % 2;
        transpose_tile(cls_w, cwt, H3_, NL_, kt, nt, t, tileLds);
        if (nt == 1) {              // zero pad rows 40..47 for this k-range
            int tx = t & 31, ty = t >> 5;
            cwt[(size_t)(40 + ty) * H3_ + kt * 32 + tx] = __float2bfloat16(0.0f);
        }
    } else {
        int i = blk - 2096;         // desc norm, D=384
        const float* x = desc + (size_t)i * DS_;
        float ss = 0.0f;
        for (int d = t; d < DS_; d += 256) { float v = x[d]; ss += v * v; }
        ss = block_reduce_sum(ss, tileLds);
        float inv = 1.0f / fmaxf(sqrtf(ss), EPS_);
        __hip_bfloat16* o = desc_nb + (size_t)i * DS_;
        for (int d = t; d < DS_; d += 256) o[d] = __float2bfloat16(x[d] * inv);
    }
}

// ---------------- GEMM device bodies (double-buffered, prefetched) ----------------
// One __syncthreads per 32-wide K step; global prefetch of tile k+1 issued
// before the MFMA phase so HBM/L2 latency hides under compute.

// 128x128 tile MFMA: C = tanh?(A@B^T + bias)
__device__ __forceinline__ void gemm128_body(
    const __hip_bfloat16* __restrict__ A, const __hip_bfloat16* __restrict__ Bp,
    const float* __restrict__ bias, float* __restrict__ C,
    int K, int lda, int ldb, int ldc, int fuse_tanh, int bx, int by,
    __hip_bfloat16* As0, __hip_bfloat16* Bs0,
    __hip_bfloat16* As1, __hip_bfloat16* Bs1)
{
    int tid  = threadIdx.x;
    int lane = tid & 63;
    int wave = tid >> 6;
    int wm = (wave >> 1) * 64;
    int wn = (wave & 1) * 64;
    int lr = lane & 15;
    int quad = lane >> 4;
    int rowBase = by * 128;
    int colBase = bx * 128;

    f4_t acc[4][4];
#pragma unroll
    for (int i = 0; i < 4; ++i)
#pragma unroll
        for (int j = 0; j < 4; ++j) acc[i][j] = (f4_t){0.f, 0.f, 0.f, 0.f};

    int sr = tid >> 2, sc = tid & 3;
    const __hip_bfloat16* Abase = A + (size_t)(rowBase + sr) * lda + sc * 8;
    const __hip_bfloat16* Bbase = Bp + (size_t)(colBase + sr) * ldb + sc * 8;
    size_t a64 = (size_t)64 * lda, b64 = (size_t)64 * ldb;

    // stage iteration 0 into buffer 0
    *(bf8_t*)&As0[sr * LDSPAD + sc * 8]        = *(const bf8_t*)(Abase);
    *(bf8_t*)&As0[(sr + 64) * LDSPAD + sc * 8] = *(const bf8_t*)(Abase + a64);
    *(bf8_t*)&Bs0[sr * LDSPAD + sc * 8]        = *(const bf8_t*)(Bbase);
    *(bf8_t*)&Bs0[(sr + 64) * LDSPAD + sc * 8] = *(const bf8_t*)(Bbase + b64);
    __syncthreads();

    int nIter = K >> 5;
    for (int i = 0; i < nIter; ++i) {
        __hip_bfloat16* Asc = (i & 1) ? As1 : As0;
        __hip_bfloat16* Bsc = (i & 1) ? Bs1 : Bs0;
        __hip_bfloat16* Asn = (i & 1) ? As0 : As1;
        __hip_bfloat16* Bsn = (i & 1) ? Bs0 : Bs1;
        bf8_t pa0, pa1, pb0, pb1;
        bool pf = (i + 1 < nIter);
        if (pf) {                       // issue next-tile loads BEFORE compute
            int k = (i + 1) << 5;
            pa0 = *(const bf8_t*)(Abase + k);
            pa1 = *(const bf8_t*)(Abase + a64 + k);
            pb0 = *(const bf8_t*)(Bbase + k);
            pb1 = *(const bf8_t*)(Bbase + b64 + k);
        }
        bf8_t af[4], bfr[4];
#pragma unroll
        for (int f = 0; f < 4; ++f) {
            af[f]  = *(const bf8_t*)&Asc[(wm + f*16 + lr) * LDSPAD + quad * 8];
            bfr[f] = *(const bf8_t*)&Bsc[(wn + f*16 + lr) * LDSPAD + quad * 8];
        }
#pragma unroll
        for (int ii = 0; ii < 4; ++ii)
#pragma unroll
            for (int j = 0; j < 4; ++j)
                acc[ii][j] = __builtin_amdgcn_mfma_f32_16x16x32_bf16(af[ii], bfr[j], acc[ii][j], 0, 0, 0);
        if (pf) {
            *(bf8_t*)&Asn[sr * LDSPAD + sc * 8]        = pa0;
            *(bf8_t*)&Asn[(sr + 64) * LDSPAD + sc * 8] = pa1;
            *(bf8_t*)&Bsn[sr * LDSPAD + sc * 8]        = pb0;
            *(bf8_t*)&Bsn[(sr + 64) * LDSPAD + sc * 8] = pb1;
        }
        __syncthreads();
    }
#pragma unroll
    for (int j = 0; j < 4; ++j) {
        int col = colBase + wn + j*16 + lr;
        float bv = bias ? bias[col] : 0.0f;
#pragma unroll
        for (int i = 0; i < 4; ++i) {
            int row0 = rowBase + wm + i*16 + quad*4;
#pragma unroll
            for (int r = 0; r < 4; ++r) {
                float v = acc[i][j][r] + bv;
                if (fuse_tanh) v = tanhf(v);
                C[(size_t)(row0 + r) * ldc + col] = v;
            }
        }
    }
}

// 64x64 tile MFMA over K columns starting at kBase: C = scale*(A[:,kBase:kBase+K]@B[:,kBase:kBase+K]^T)
__device__ __forceinline__ void gemm64_body(
    const __hip_bfloat16* __restrict__ A, const __hip_bfloat16* __restrict__ Bp,
    float* __restrict__ C,
    int K, int kBase, int lda, int ldb, int ldc, float scale, int bx, int by,
    __hip_bfloat16* As0, __hip_bfloat16* Bs0,
    __hip_bfloat16* As1, __hip_bfloat16* Bs1)
{
    int tid  = threadIdx.x;
    int lane = tid & 63;
    int wave = tid >> 6;
    int lr = lane & 15;
    int quad = lane >> 4;
    int rowBase = by * 64;
    int colBase = bx * 64;

    f4_t acc[4];
#pragma unroll
    for (int i = 0; i < 4; ++i) acc[i] = (f4_t){0.f, 0.f, 0.f, 0.f};

    int sr = tid >> 2, sc = tid & 3;
    const __hip_bfloat16* Abase = A + (size_t)(rowBase + sr) * lda + kBase + sc * 8;
    const __hip_bfloat16* Bbase = Bp + (size_t)(colBase + sr) * ldb + kBase + sc * 8;

    // stage iteration 0 into buffer 0
    *(bf8_t*)&As0[sr * LDSPAD + sc * 8] = *(const bf8_t*)(Abase);
    *(bf8_t*)&Bs0[sr * LDSPAD + sc * 8] = *(const bf8_t*)(Bbase);
    __syncthreads();

    int nIter = K >> 5;
    for (int i = 0; i < nIter; ++i) {
        __hip_bfloat16* Asc = (i & 1) ? As1 : As0;
        __hip_bfloat16* Bsc = (i & 1) ? Bs1 : Bs0;
        __hip_bfloat16* Asn = (i & 1) ? As0 : As1;
        __hip_bfloat16* Bsn = (i & 1) ? Bs0 : Bs1;
        bf8_t pa, pb;
        bool pf = (i + 1 < nIter);
        if (pf) {
            int k = (i + 1) << 5;
            pa = *(const bf8_t*)(Abase + k);
            pb = *(const bf8_t*)(Bbase + k);
        }
        bf8_t bfr = *(const bf8_t*)&Bsc[(wave*16 + lr) * LDSPAD + quad * 8];
#pragma unroll
        for (int f = 0; f < 4; ++f) {
            bf8_t af = *(const bf8_t*)&Asc[(f*16 + lr) * LDSPAD + quad * 8];
            acc[f] = __builtin_amdgcn_mfma_f32_16x16x32_bf16(af, bfr, acc[f], 0, 0, 0);
        }
        if (pf) {
            *(bf8_t*)&Asn[sr * LDSPAD + sc * 8] = pa;
            *(bf8_t*)&Bsn[sr * LDSPAD + sc * 8] = pb;
        }
        __syncthreads();
    }
    int col = colBase + wave*16 + lr;
#pragma unroll
    for (int f = 0; f < 4; ++f) {
        int row0 = rowBase + f*16 + quad*4;
#pragma unroll
        for (int r = 0; r < 4; ++r)
            C[(size_t)(row0 + r) * ldc + col] = acc[f][r] * scale;
    }
}

// cls logits + CE, 16 rows/block, K split across 4 waves, no LDS staging.
__device__ __forceinline__ void cls_ce_body(
    const __hip_bfloat16* __restrict__ rh, const __hip_bfloat16* __restrict__ cwt,
    const float* __restrict__ cls_b, const int* __restrict__ labels,
    float* __restrict__ acc, int rowBase, float* lgp /* 4*16*48 floats */)
{
    int tid  = threadIdx.x;
    int lane = tid & 63;
    int wave = tid >> 6;
    int lr = lane & 15;
    int quad = lane >> 4;

    f4_t a3[3];
#pragma unroll
    for (int j = 0; j < 3; ++j) a3[j] = (f4_t){0.f, 0.f, 0.f, 0.f};

    int kw0 = wave * (H3_ / 4);    // 576 per wave
    const __hip_bfloat16* aRow = rh + (size_t)(rowBase + lr) * H3_ + quad * 8;
#pragma unroll 2
    for (int s = 0; s < 18; ++s) {
        int k = kw0 + s * 32;
        bf8_t af = *(const bf8_t*)(aRow + k);
#pragma unroll
        for (int j = 0; j < 3; ++j) {
            bf8_t bfr = *(const bf8_t*)(cwt + (size_t)(j*16 + lr) * H3_ + k + quad * 8);
            a3[j] = __builtin_amdgcn_mfma_f32_16x16x32_bf16(af, bfr, a3[j], 0, 0, 0);
        }
    }
    // partials -> LDS: lgp[w*768 + row*48 + col]
#pragma unroll
    for (int j = 0; j < 3; ++j) {
        int col = j*16 + lr;
#pragma unroll
        for (int r = 0; r < 4; ++r)
            lgp[wave * 768 + (quad*4 + r) * 48 + col] = a3[j][r];
    }
    __syncthreads();
    // combine 4 partials + bias
    for (int idx = tid; idx < 768; idx += 256) {
        int col = idx % 48;
        float s = lgp[idx] + lgp[768 + idx] + lgp[1536 + idx] + lgp[2304 + idx];
        s = (col < NL_) ? (s + cls_b[col]) : -INFINITY;
        lgp[idx] = s;
    }
    __syncthreads();
    if (tid < 64) {
        float ce = 0.0f;
        if (tid < 16) {
            const float* Lr = &lgp[tid * 48];
            float m = -INFINITY;
            for (int c = 0; c < NL_; ++c) m = fmaxf(m, Lr[c]);
            float s = 0.0f;
            for (int c = 0; c < NL_; ++c) s += expf(Lr[c] - m);
            ce = logf(s) + m - Lr[labels[rowBase + tid]];
        }
        for (int off = 8; off >= 1; off >>= 1) ce += __shfl_down(ce, off);
        if (tid == 0) atomicAdd(acc + 0, ce * (1.0f / (float)B_));
    }
}

// ---------------- kernel 2: dense(96) + fc split-K(96) + cls_ce(32) = 224 blocks ----------------
__global__ __launch_bounds__(256) void gemms_kernel(
    const __hip_bfloat16* __restrict__ toks_bf, const __hip_bfloat16* __restrict__ dwt,
    const float* __restrict__ dense_b, float* __restrict__ toks_out,
    const __hip_bfloat16* __restrict__ rh_bf, const __hip_bfloat16* __restrict__ fwt,
    float* __restrict__ relP0, float* __restrict__ relP1,
    const __hip_bfloat16* __restrict__ cwt, const float* __restrict__ cls_b,
    const int* __restrict__ labels, float* __restrict__ acc)
{
    __shared__ __align__(16) char smem[4 * 128 * LDSPAD * 2];   // 40960 B
    __hip_bfloat16* s0 = (__hip_bfloat16*)smem;
    int blk = blockIdx.x;
    if (blk < 96) {
        gemm128_body(toks_bf, dwt, dense_b, toks_out, H_, H_, H_, H_, 1,
                     blk % 6, blk / 6,
                     s0, s0 + 128*LDSPAD, s0 + 2*128*LDSPAD, s0 + 3*128*LDSPAD);
    } else if (blk < 192) {
        int q = blk - 96;
        int half = q >= 48 ? 1 : 0;
        int q2 = q - 48 * half;
        gemm64_body(rh_bf, fwt, half ? relP1 : relP0, H3_/2, half * (H3_/2),
                    H3_, H3_, DS_, 1.0f, q2 % 6, q2 / 6,
                    s0, s0 + 64*LDSPAD, s0 + 2*64*LDSPAD, s0 + 3*64*LDSPAD);
    } else {
        cls_ce_body(rh_bf, cwt, cls_b, labels, acc, (blk - 192) * 16, (float*)smem);
    }
}

// ---------------- kernel 3: rel norm (512, sums fc partials + bias) + z norm (1024) ----------------
__global__ __launch_bounds__(256) void znorm_kernel(
    const float* __restrict__ relP0, const float* __restrict__ relP1,
    const float* __restrict__ fc_b, const float* __restrict__ toks_out,
    __hip_bfloat16* __restrict__ rel_nb, __hip_bfloat16* __restrict__ z_bf)
{
    __shared__ float sh[4];
    int blk = blockIdx.x, t = threadIdx.x;
    if (blk < 512) {
        const f4_t* p0 = (const f4_t*)(relP0 + (size_t)blk * DS_);
        const f4_t* p1 = (const f4_t*)(relP1 + (size_t)blk * DS_);
        const f4_t* bb = (const f4_t*)fc_b;
        f4_t v = (f4_t){0.f, 0.f, 0.f, 0.f};
        float ss = 0.0f;
        if (t < 96) {                           // 96 float4 = 384 elems
            v = p0[t] + p1[t] + bb[t];
            ss = v[0]*v[0] + v[1]*v[1] + v[2]*v[2] + v[3]*v[3];
        }
        ss = block_reduce_sum(ss, sh);
        float inv = 1.0f / fmaxf(sqrtf(ss), EPS_);
        if (t < 96) {
            s4_t o = { bfbits(v[0]*inv), bfbits(v[1]*inv), bfbits(v[2]*inv), bfbits(v[3]*inv) };
            ((s4_t*)(rel_nb + (size_t)blk * DS_))[t] = o;
        }
    } else {
        int r = blk - 512;
        const f4_t* xv = (const f4_t*)(toks_out + (size_t)r * 2 * H_);  // 384 float4
        f4_t v0 = xv[t];
        f4_t v1 = (t < 128) ? xv[256 + t] : (f4_t){0.f, 0.f, 0.f, 0.f};
        float ss = v0[0]*v0[0] + v0[1]*v0[1] + v0[2]*v0[2] + v0[3]*v0[3]
                 + v1[0]*v1[0] + v1[1]*v1[1] + v1[2]*v1[2] + v1[3]*v1[3];
        ss = block_reduce_sum(ss, sh);
        float inv = 1.0f / fmaxf(sqrtf(ss), EPS_);
        s4_t* ov = (s4_t*)(z_bf + (size_t)r * 2 * H_);
        s4_t o0 = { bfbits(v0[0]*inv), bfbits(v0[1]*inv), bfbits(v0[2]*inv), bfbits(v0[3]*inv) };
        ov[t] = o0;
        if (t < 128) {
            s4_t o1 = { bfbits(v1[0]*inv), bfbits(v1[1]*inv), bfbits(v1[2]*inv), bfbits(v1[3]*inv) };
            ov[256 + t] = o1;
        }
    }
}

// ---------------- kernel 4: C1 (64) + C2 split-K (128) = 192 blocks ----------------
__global__ __launch_bounds__(256) void c1c2_kernel(
    const __hip_bfloat16* __restrict__ rel_nb, const __hip_bfloat16* __restrict__ desc_nb,
    const __hip_bfloat16* __restrict__ z_bf,
    float* __restrict__ C1, float* __restrict__ C2a, float* __restrict__ C2b)
{
    __shared__ __align__(16) char smem[4 * 64 * LDSPAD * 2];    // 20480 B
    __hip_bfloat16* s0 = (__hip_bfloat16*)smem;
    __hip_bfloat16* As0 = s0;
    __hip_bfloat16* Bs0 = s0 + 64*LDSPAD;
    __hip_bfloat16* As1 = s0 + 2*64*LDSPAD;
    __hip_bfloat16* Bs1 = s0 + 3*64*LDSPAD;
    int blk = blockIdx.x;
    if (blk < 64) {
        gemm64_body(rel_nb, desc_nb, C1, DS_, 0, DS_, DS_, B_, 1.0f,
                    blk % 8, blk / 8, As0, Bs0, As1, Bs1);
    } else {
        int q = blk - 64;
        int half = q >= 64 ? 1 : 0;
        int q2 = q - 64 * half;
        gemm64_body(z_bf, z_bf + 2*H_, half ? C2b : C2a, H_, half * H_,
                    4*H_, 4*H_, B_, 1.0f/TEMP_, q2 % 8, q2 / 8, As0, Bs0, As1, Bs1);
    }
}

// ---------------- kernel 5: margin (512) + cos-CE (512, sums C2 partials) + finalize ----------------
__global__ __launch_bounds__(256) void tail_kernel(
    const float* __restrict__ C1, const float* __restrict__ C2a, const float* __restrict__ C2b,
    const int* __restrict__ labels, float* __restrict__ acc,
    int* __restrict__ done, float* __restrict__ out)
{
    __shared__ float sh[4];
    int blk = blockIdx.x, t = threadIdx.x;
    if (blk < 512) {
        int i = blk;
        int li = labels[i];
        const float* row = C1 + (size_t)i * B_;
        int j0 = t, j1 = t + 256;
        float m = -INFINITY;
        if (labels[j0] != li) m = row[j0];
        if (labels[j1] != li) m = fmaxf(m, row[j1]);
        float negmax = block_reduce_max(m, sh);
        if (t == 0) {
            float neg = fmaxf(negmax, 0.0f);
            float term = neg - row[i] + GAMMA_;
            if (term > 0.0f) atomicAdd(acc + 1, term);
        }
    } else {
        int i = blk - 512;
        const float* ra = C2a + (size_t)i * B_;
        const float* rb = C2b + (size_t)i * B_;
        int j0 = t, j1 = t + 256;
        float va = ra[j0] + rb[j0];
        float vb = ra[j1] + rb[j1];
        float m = block_reduce_max(fmaxf(va, vb), sh);
        float s = expf(va - m) + expf(vb - m);
        s = block_reduce_sum(s, sh);
        if (t == 0) {
            float pos = ra[i] + rb[i];
            atomicAdd(acc + 2, (logf(s) + m - pos) * (1.0f / (float)B_));
        }
    }
    __threadfence();
    if (t == 0) {
        int prev = atomicAdd(done, 1);
        if (prev == 1023) {
            // atomic reads: device-scope, safe across XCD L2s
            float a0 = atomicAdd(acc + 0, 0.0f);
            float a1 = atomicAdd(acc + 1, 0.0f);
            float a2 = atomicAdd(acc + 2, 0.0f);
            out[0] = a0 + (1.0f - ALPHA_) * a1 + ALPHA_ * a2;
        }
    }
}

// ---------------- launch ----------------

extern "C" void kernel_launch(void* const* d_in, const int* in_sizes, int n_in,
                              void* d_out, int out_size, void* d_ws, size_t ws_size,
                              hipStream_t stream) {
    const float* bert     = (const float*)d_in[0];
    const float* desc     = (const float*)d_in[1];
    const float* dense_w  = (const float*)d_in[2];
    const float* dense_b  = (const float*)d_in[3];
    const float* cls_w    = (const float*)d_in[4];
    const float* cls_b    = (const float*)d_in[5];
    const float* fc_w     = (const float*)d_in[6];
    const float* fc_b     = (const float*)d_in[7];
    const int*   eidx     = (const int*)d_in[8];
    const int*   labels   = (const int*)d_in[9];
    float* out = (float*)d_out;

    float* fp = (float*)d_ws;
    __hip_bfloat16* rh_bf   = (__hip_bfloat16*)fp; fp += (size_t)B_*H3_/2;
    __hip_bfloat16* toks_bf = (__hip_bfloat16*)fp; fp += (size_t)B_*4*H_/2;
    __hip_bfloat16* dwt_bf  = (__hip_bfloat16*)fp; fp += (size_t)H_*H_/2;
    __hip_bfloat16* fwt_bf  = (__hip_bfloat16*)fp; fp += (size_t)DS_*H3_/2;
    __hip_bfloat16* cwt_bf  = (__hip_bfloat16*)fp; fp += (size_t)48*H3_/2;   // padded to 48 rows
    __hip_bfloat16* desc_nb = (__hip_bfloat16*)fp; fp += (size_t)B_*DS_/2;
    __hip_bfloat16* rel_nb  = (__hip_bfloat16*)fp; fp += (size_t)B_*DS_/2;
    __hip_bfloat16* z_bf    = (__hip_bfloat16*)fp; fp += (size_t)B_*4*H_/2;
    float* toks_out = fp; fp += (size_t)B_*4*H_;
    float* relP0    = fp; fp += (size_t)B_*DS_;
    float* relP1    = fp; fp += (size_t)B_*DS_;
    float* C1       = fp; fp += (size_t)B_*B_;
    float* C2a      = fp; fp += (size_t)B_*B_;
    float* C2b      = fp; fp += (size_t)B_*B_;
    float* acc      = fp; fp += 4;
    int*   done     = (int*)fp;

    // 1. prep: gather + transposes + desc norm (+ zero acc/done)
    prep_kernel<<<2608, 256, 0, stream>>>(bert, eidx, dense_w, fc_w, cls_w, desc,
                                          rh_bf, toks_bf, dwt_bf, fwt_bf, cwt_bf,
                                          desc_nb, acc, done);

    // 2. dense + fc(split-K) + cls_ce (independent, one launch, 224 blocks)
    gemms_kernel<<<224, 256, 0, stream>>>(toks_bf, dwt_bf, dense_b, toks_out,
                                          rh_bf, fwt_bf, relP0, relP1,
                                          cwt_bf, cls_b, labels, acc);

    // 3. rel (sum partials + bias) + z norms
    znorm_kernel<<<1536, 256, 0, stream>>>(relP0, relP1, fc_b, toks_out, rel_nb, z_bf);

    // 4. C1 + C2 (split-K, 192 blocks)
    c1c2_kernel<<<192, 256, 0, stream>>>(rel_nb, desc_nb, z_bf, C1, C2a, C2b);

    // 5. margin + cos-CE + finalize (last block writes out)
    tail_kernel<<<1024, 256, 0, stream>>>(C1, C2a, C2b, labels, acc, done, out);
}